// Round 7
// baseline (237.194 us; speedup 1.0000x reference)
//
#include <hip/hip_runtime.h>
#include <hip/hip_fp16.h>
#include <math.h>

#define N_NODES 100000
#define N_EDGES 3200000
#define D_IN    128
#define H1      16

#define BSH   7
#define NPB   128                      // nodes per bucket
#define NB    782                      // ceil(100000/128)
#define CAP   6656                     // region capacity (padded fill ~6140, +5 sigma)
#define PBLK  256
#define CHUNK 12500                    // N_EDGES / PBLK exact
#define MROWS 64

// eop layout: NB regions of CAP uints, region base 64B-aligned (CAP%16==0).
// After k_partition: packed (src<<7 | dloc) runs, each (block,bucket) run padded
// to a 16-edge (64B) multiple with 0xFFFFFFFF sentinels -> every line is
// written by exactly one block (no cross-XCD partial-line RMW).
// After k_build: plain src, grouped (CSR) by dst node.

__global__ __launch_bounds__(512) void k_zero(int* __restrict__ cursor) {
    int t = blockIdx.x * 512 + threadIdx.x;
    if (t < NB) cursor[t] = 0;
}

// ---- partition: count(+rank) -> padded bulk reserve -> atomic-free scatter ----
__global__ __launch_bounds__(512) void k_partition(const int* __restrict__ ei,
                                                   int* __restrict__ cursor,
                                                   unsigned int* __restrict__ eop) {
    __shared__ int h[NB];
    __shared__ int resv[NB];
    __shared__ unsigned char rank8[CHUNK];   // 12.5 KB; max count/run ~40 < 255
    int t = threadIdx.x;
    for (int i = t; i < NB; i += 512) h[i] = 0;
    __syncthreads();
    int c0 = blockIdx.x * CHUNK;
    const int* srcs = ei + c0;
    const int* dsts = ei + N_EDGES + c0;
    for (int i = t; i < CHUNK; i += 512)
        rank8[i] = (unsigned char)atomicAdd(&h[dsts[i] >> BSH], 1);
    __syncthreads();
    for (int b = t; b < NB; b += 512) {
        int c  = h[b];
        int cp = (c + 15) & ~15;             // pad run to 64B multiple
        resv[b] = cp ? atomicAdd(&cursor[b], cp) : 0;   // stays 16-aligned
    }
    __syncthreads();
    for (int i = t; i < CHUNK; i += 512) {
        int s = srcs[i];
        int d = dsts[i];
        int b = d >> BSH;
        int pos = resv[b] + (int)rank8[i];
        if (pos < CAP)   // statistically impossible overflow guard
            eop[(size_t)b * CAP + pos] = ((unsigned)s << BSH) | (unsigned)(d & (NPB - 1));
    }
    // sentinel-fill the pad tail of each of this block's runs (same lines we own)
    for (int b = t; b < NB; b += 512) {
        int c  = h[b];
        int cp = (c + 15) & ~15;
        int base = resv[b];
        for (int k = c; k < cp; ++k) {
            int pos = base + k;
            if (pos < CAP) eop[(size_t)b * CAP + pos] = 0xFFFFFFFFu;
        }
    }
}

// ---- build: in-bucket sort to node CSR (rank trick, sentinel skip) ----
__global__ __launch_bounds__(512) void k_build(const int* __restrict__ cursor,
                                               unsigned int* __restrict__ eop,
                                               int* __restrict__ nstart,
                                               int* __restrict__ ndeg,
                                               float* __restrict__ dinv) {
    __shared__ unsigned int els[CAP];   // 26 KB
    __shared__ int cnt[NPB];
    __shared__ int off[NPB];
    int t = threadIdx.x, b = blockIdx.x;
    if (t < NPB) cnt[t] = 0;
    __syncthreads();
    int n = cursor[b]; if (n > CAP) n = CAP;   // padded fill
    unsigned int* reg = eop + (size_t)b * CAP;
    for (int i = t; i < n; i += 512) {
        unsigned int v = reg[i];
        if ((int)v >= 0) {                       // real entry (bit31==0)
            int r = atomicAdd(&cnt[v & (NPB - 1)], 1);   // node rank, <128
            v |= (unsigned)r << 24;              // src:17b<<7 | dloc:7b | rank:7b
        }
        els[i] = v;
    }
    __syncthreads();
    int val = (t < NPB) ? cnt[t] : 0;
    if (t < NPB) off[t] = val;
    __syncthreads();
    for (int o = 1; o < NPB; o <<= 1) {          // inclusive Hillis-Steele
        int u = 0;
        if (t < NPB && t >= o) u = off[t - o];
        __syncthreads();
        if (t < NPB) off[t] += u;
        __syncthreads();
    }
    if (t < NPB) {
        int ex = off[t] - val;                   // exclusive
        int node = (b << BSH) + t;
        if (node < N_NODES) {
            nstart[node] = b * CAP + ex;
            ndeg[node]   = val;
            dinv[node]   = rsqrtf((float)(val + 1));   // +1 self-loop
        }
        off[t] = ex;
    }
    __syncthreads();
    for (int i = t; i < n; i += 512) {
        unsigned int u = els[i];
        if ((int)u >= 0) {
            int dloc = u & (NPB - 1);
            int r    = (u >> 24) & 0x7F;
            reg[off[dloc] + r] = (u >> BSH) & 0x1FFFF;   // plain src, CSR order
        }
    }
}

// ---- matmul: wave = 64 rows x 4 cols, x in LDS (pad 129), W uniform loads ----
__global__ __launch_bounds__(256) void k_mm1(const float* __restrict__ x,
                                             const float* __restrict__ W1,
                                             const float* __restrict__ dinv,
                                             __half* __restrict__ h1h) {
    __shared__ float sX[MROWS][D_IN + 1];   // 33 KB
    int t = threadIdx.x;
    int r0 = blockIdx.x * MROWS;
    for (int i = t; i < MROWS * (D_IN / 4); i += 256) {
        int row = i >> 5, c4 = i & 31;
        int grow = r0 + row;
        float4 v = (grow < N_NODES) ? ((const float4*)x)[(size_t)grow * 32 + c4]
                                    : make_float4(0.f, 0.f, 0.f, 0.f);
        sX[row][c4 * 4 + 0] = v.x; sX[row][c4 * 4 + 1] = v.y;
        sX[row][c4 * 4 + 2] = v.z; sX[row][c4 * 4 + 3] = v.w;
    }
    __syncthreads();
    int lane = t & 63;
    int c0 = __builtin_amdgcn_readfirstlane((t >> 6) * 4);
    float a0 = 0.f, a1 = 0.f, a2 = 0.f, a3 = 0.f;
#pragma unroll 4
    for (int d = 0; d < D_IN; ++d) {
        float xv = sX[lane][d];
        a0 = fmaf(xv, W1[d * 16 + c0 + 0], a0);
        a1 = fmaf(xv, W1[d * 16 + c0 + 1], a1);
        a2 = fmaf(xv, W1[d * 16 + c0 + 2], a2);
        a3 = fmaf(xv, W1[d * 16 + c0 + 3], a3);
    }
    int grow = r0 + lane;
    if (grow < N_NODES) {
        float di = dinv[grow];
        __half2* o = (__half2*)(h1h + (size_t)grow * H1 + c0);
        o[0] = __floats2half2_rn(a0 * di, a1 * di);
        o[1] = __floats2half2_rn(a2 * di, a3 * di);
    }
}

// ---- layer-1 agg: 16 lanes/node, register accumulate, fused relu+W2 ----
__global__ __launch_bounds__(256) void k_agg1(const unsigned int* __restrict__ eop,
                                              const int* __restrict__ nstart,
                                              const int* __restrict__ ndeg,
                                              const __half* __restrict__ h1h,
                                              const float* __restrict__ dinv,
                                              const float* __restrict__ b1,
                                              const float* __restrict__ W2,
                                              float2* __restrict__ h2f) {
    int t = threadIdx.x;
    int g = t >> 4, l = t & 15;
    int node = blockIdx.x * 16 + g;          // 6250*16 == N exactly
    int e0 = nstart[node], e1 = e0 + ndeg[node];
    float acc = 0.f;
    int j = e0;
    for (; j + 4 <= e1; j += 4) {
        int s0 = eop[j], s1 = eop[j + 1], s2 = eop[j + 2], s3 = eop[j + 3];
        acc += __half2float(h1h[s0 * H1 + l]) + __half2float(h1h[s1 * H1 + l])
             + __half2float(h1h[s2 * H1 + l]) + __half2float(h1h[s3 * H1 + l]);
    }
    for (; j < e1; ++j) acc += __half2float(h1h[(int)eop[j] * H1 + l]);
    float di = dinv[node];
    float s  = acc + __half2float(h1h[node * H1 + l]);   // + self-loop
    float h  = fmaxf(fmaf(di, s, b1[l]), 0.f);
    float p0 = h * W2[2 * l], p1 = h * W2[2 * l + 1];
#pragma unroll
    for (int off = 1; off < 16; off <<= 1) {
        p0 += __shfl_xor(p0, off);
        p1 += __shfl_xor(p1, off);
    }
    if (l == 0) h2f[node] = make_float2(p0 * di, p1 * di);
}

// ---- layer-2 agg: 4 lanes/node + b2 + log_softmax ----
__global__ __launch_bounds__(256) void k_agg2(const unsigned int* __restrict__ eop,
                                              const int* __restrict__ nstart,
                                              const int* __restrict__ ndeg,
                                              const float2* __restrict__ h2f,
                                              const float* __restrict__ dinv,
                                              const float* __restrict__ b2,
                                              float* __restrict__ out) {
    int tg = blockIdx.x * 256 + threadIdx.x;
    int node = tg >> 2, l = tg & 3;
    if (node >= N_NODES) return;
    int e0 = nstart[node], e1 = e0 + ndeg[node];
    float ax = 0.f, ay = 0.f;
    for (int j = e0 + l; j < e1; j += 4) {
        float2 m = h2f[eop[j]];
        ax += m.x; ay += m.y;
    }
    ax += __shfl_xor(ax, 1); ay += __shfl_xor(ay, 1);
    ax += __shfl_xor(ax, 2); ay += __shfl_xor(ay, 2);
    if (l == 0) {
        float di = dinv[node];
        float2 self = h2f[node];
        float a0 = fmaf(di, ax + self.x, b2[0]);
        float a1 = fmaf(di, ay + self.y, b2[1]);
        float m  = fmaxf(a0, a1);
        float lg = logf(expf(a0 - m) + expf(a1 - m));
        out[2 * node]     = a0 - m - lg;
        out[2 * node + 1] = a1 - m - lg;
    }
}

extern "C" void kernel_launch(void* const* d_in, const int* in_sizes, int n_in,
                              void* d_out, int out_size, void* d_ws, size_t ws_size,
                              hipStream_t stream) {
    const float* x  = (const float*)d_in[0];
    const int*   ei = (const int*)d_in[1];
    const float* W1 = (const float*)d_in[2];
    const float* b1 = (const float*)d_in[3];
    const float* W2 = (const float*)d_in[4];
    const float* b2 = (const float*)d_in[5];
    float* out = (float*)d_out;

    // workspace carve (~26 MB), eop region 64B-aligned
    int*          cursor = (int*)d_ws;                       // 1024
    int*          nstart = cursor + 1024;                    // N (pad 100352)
    int*          ndeg   = nstart + 100352;                  // N (pad 100352)
    float*        dinv   = (float*)(ndeg + 100352);          // N (pad 100352)
    __half*       h1h    = (__half*)(dinv + 100352);         // N*16 halves, 3.2 MB
    float2*       h2f    = (float2*)(h1h + (size_t)100352 * H1);  // N float2
    unsigned int* eop    = (unsigned int*)(h2f + 100352);    // NB*CAP = 20.8 MB

    k_zero     <<<(NB + 511) / 512, 512, 0, stream>>>(cursor);
    k_partition<<<PBLK, 512, 0, stream>>>(ei, cursor, eop);
    k_build    <<<NB,   512, 0, stream>>>(cursor, eop, nstart, ndeg, dinv);
    k_mm1      <<<(N_NODES + MROWS - 1) / MROWS, 256, 0, stream>>>(x, W1, dinv, h1h);
    k_agg1     <<<N_NODES / 16, 256, 0, stream>>>(eop, nstart, ndeg, h1h, dinv, b1, W2, h2f);
    k_agg2     <<<(N_NODES * 4 + 255) / 256, 256, 0, stream>>>(eop, nstart, ndeg, h2f, dinv, b2, out);
}

// Round 8
// 222.614 us; speedup vs baseline: 1.0655x; 1.0655x over previous
//
#include <hip/hip_runtime.h>
#include <hip/hip_fp16.h>
#include <math.h>

#define N_NODES 100000
#define N_EDGES 3200000
#define D_IN    128
#define H1      16

#define BSH     8
#define NPB     256                    // nodes per bucket
#define NB      391                    // ceil(100000/256)
#define CAP     13056                  // eop region capacity (x16; padded fill ~12280 +5.7sigma)
#define PBLK    512
#define CHUNK   6250                   // N_EDGES / PBLK exact
#define ELS_CAP 12128                  // >= 6250 + 391*15 = 12115, multiple of 16
#define NLINES  (ELS_CAP / 16)         // 758
#define MROWS   64

// eop: NB regions of CAP uints (region base 64B-aligned).
// After k_partition: packed (src<<8 | dloc) runs, run per (block,bucket) padded
// to 16-edge (64B) multiples with 0xFFFFFFFF sentinels; the block locally
// bucket-sorts its chunk in LDS and writes it out COALESCED so every 64B line
// is produced by one full-line write burst (no partial-line L2 evictions).
// After k_build: plain src, grouped (CSR) by dst node, compact at region front.

__global__ __launch_bounds__(512) void k_zero(int* __restrict__ cursor) {
    int t = threadIdx.x;
    if (t < NB) cursor[t] = 0;
}

// ---- partition: rank -> scan -> LDS bucket-sort -> coalesced full-line writeout ----
__global__ __launch_bounds__(512) void k_partition(const int* __restrict__ ei,
                                                   int* __restrict__ cursor,
                                                   unsigned int* __restrict__ eop) {
    __shared__ int h[512];                       // per-bucket counts (pad to 512)
    __shared__ int loff[512];                    // scan array -> exclusive local offsets
    __shared__ int resv[NB];                     // global region offsets
    __shared__ unsigned short owner[NLINES];     // line -> bucket
    __shared__ unsigned char rank8[CHUNK];       // per-edge rank in its run (<255)
    __shared__ unsigned int els[ELS_CAP];        // 48.5 KB staging
    int t = threadIdx.x;
    h[t] = 0;
    __syncthreads();
    int c0 = blockIdx.x * CHUNK;
    const int* srcs = ei + c0;
    const int* dsts = ei + N_EDGES + c0;
    for (int i = t; i < CHUNK; i += 512)
        rank8[i] = (unsigned char)atomicAdd(&h[dsts[i] >> BSH], 1);
    __syncthreads();
    int cp = (h[t] + 15) & ~15;                  // run padded to 64B multiple
    loff[t] = cp;
    __syncthreads();
    for (int o = 1; o < 512; o <<= 1) {          // inclusive Hillis-Steele
        int u = (t >= o) ? loff[t - o] : 0;
        __syncthreads();
        loff[t] += u;
        __syncthreads();
    }
    int inc = loff[t];
    int totalpad = loff[511];                    // <= ELS_CAP by construction
    int ex = inc - cp;
    __syncthreads();
    loff[t] = ex;                                // now exclusive
    if (t < NB && cp) {
        resv[t] = atomicAdd(&cursor[t], cp);     // stays 16-aligned
        int l0 = ex >> 4;
        for (int k = 0; k < (cp >> 4); ++k) owner[l0 + k] = (unsigned short)t;
    }
    for (int i = t; i < totalpad; i += 512) els[i] = 0xFFFFFFFFu;   // sentinels
    __syncthreads();
    for (int i = t; i < CHUNK; i += 512) {       // LDS bucket-sort scatter
        int s = srcs[i];
        int d = dsts[i];
        int b = d >> BSH;
        els[loff[b] + (int)rank8[i]] = ((unsigned)s << BSH) | (unsigned)(d & (NPB - 1));
    }
    __syncthreads();
    for (int i = t; i < totalpad; i += 512) {    // coalesced: full 64B lines
        int b   = owner[i >> 4];
        int pos = resv[b] + (i - loff[b]);
        if (pos < CAP)                           // statistically impossible guard
            eop[(size_t)b * CAP + pos] = els[i];
    }
}

// ---- build: stage region in LDS, count, scan, recompute-rank write-back ----
__global__ __launch_bounds__(512) void k_build(const int* __restrict__ cursor,
                                               unsigned int* __restrict__ eop,
                                               int* __restrict__ nstart,
                                               int* __restrict__ ndeg,
                                               float* __restrict__ dinv) {
    __shared__ unsigned int els[CAP];   // 52.2 KB
    __shared__ int cnt[NPB];
    __shared__ int off[NPB];
    __shared__ int cur[NPB];
    int t = threadIdx.x, b = blockIdx.x;
    if (t < NPB) cnt[t] = 0;
    __syncthreads();
    int n = cursor[b]; if (n > CAP) n = CAP;     // padded fill of this region
    unsigned int* reg = eop + (size_t)b * CAP;
    for (int i = t; i < n; i += 512) {
        unsigned int v = reg[i];
        els[i] = v;
        if ((int)v >= 0) atomicAdd(&cnt[v & (NPB - 1)], 1);   // real entry
    }
    __syncthreads();
    int val = (t < NPB) ? cnt[t] : 0;
    if (t < NPB) off[t] = val;
    __syncthreads();
    for (int o = 1; o < NPB; o <<= 1) {          // inclusive Hillis-Steele
        int u = 0;
        if (t < NPB && t >= o) u = off[t - o];
        __syncthreads();
        if (t < NPB) off[t] += u;
        __syncthreads();
    }
    if (t < NPB) {
        int ex = off[t] - val;                   // exclusive
        int node = (b << BSH) + t;
        if (node < N_NODES) {
            nstart[node] = b * CAP + ex;
            ndeg[node]   = val;
            dinv[node]   = rsqrtf((float)(val + 1));   // +1 self-loop
        }
        cur[t] = ex;
    }
    __syncthreads();
    for (int i = t; i < n; i += 512) {           // recompute rank, compact CSR
        unsigned int v = els[i];
        if ((int)v >= 0) {
            int r = atomicAdd(&cur[v & (NPB - 1)], 1);
            reg[r] = v >> BSH;                   // plain src
        }
    }
}

// ---- matmul: wave = 64 rows x 4 cols, x in LDS (pad 129), W uniform loads ----
__global__ __launch_bounds__(256) void k_mm1(const float* __restrict__ x,
                                             const float* __restrict__ W1,
                                             const float* __restrict__ dinv,
                                             __half* __restrict__ h1h) {
    __shared__ float sX[MROWS][D_IN + 1];   // 33 KB
    int t = threadIdx.x;
    int r0 = blockIdx.x * MROWS;
    for (int i = t; i < MROWS * (D_IN / 4); i += 256) {
        int row = i >> 5, c4 = i & 31;
        int grow = r0 + row;
        float4 v = (grow < N_NODES) ? ((const float4*)x)[(size_t)grow * 32 + c4]
                                    : make_float4(0.f, 0.f, 0.f, 0.f);
        sX[row][c4 * 4 + 0] = v.x; sX[row][c4 * 4 + 1] = v.y;
        sX[row][c4 * 4 + 2] = v.z; sX[row][c4 * 4 + 3] = v.w;
    }
    __syncthreads();
    int lane = t & 63;
    int c0 = __builtin_amdgcn_readfirstlane((t >> 6) * 4);
    float a0 = 0.f, a1 = 0.f, a2 = 0.f, a3 = 0.f;
#pragma unroll 4
    for (int d = 0; d < D_IN; ++d) {
        float xv = sX[lane][d];
        a0 = fmaf(xv, W1[d * 16 + c0 + 0], a0);
        a1 = fmaf(xv, W1[d * 16 + c0 + 1], a1);
        a2 = fmaf(xv, W1[d * 16 + c0 + 2], a2);
        a3 = fmaf(xv, W1[d * 16 + c0 + 3], a3);
    }
    int grow = r0 + lane;
    if (grow < N_NODES) {
        float di = dinv[grow];
        __half2* o = (__half2*)(h1h + (size_t)grow * H1 + c0);
        o[0] = __floats2half2_rn(a0 * di, a1 * di);
        o[1] = __floats2half2_rn(a2 * di, a3 * di);
    }
}

// ---- layer-1 agg: 16 lanes/node, register accumulate, fused relu+W2 ----
__global__ __launch_bounds__(256) void k_agg1(const unsigned int* __restrict__ eop,
                                              const int* __restrict__ nstart,
                                              const int* __restrict__ ndeg,
                                              const __half* __restrict__ h1h,
                                              const float* __restrict__ dinv,
                                              const float* __restrict__ b1,
                                              const float* __restrict__ W2,
                                              float2* __restrict__ h2f) {
    int t = threadIdx.x;
    int g = t >> 4, l = t & 15;
    int node = blockIdx.x * 16 + g;          // 6250*16 == N exactly
    int e0 = nstart[node], e1 = e0 + ndeg[node];
    float acc = 0.f;
    int j = e0;
    for (; j + 4 <= e1; j += 4) {
        int s0 = eop[j], s1 = eop[j + 1], s2 = eop[j + 2], s3 = eop[j + 3];
        acc += __half2float(h1h[s0 * H1 + l]) + __half2float(h1h[s1 * H1 + l])
             + __half2float(h1h[s2 * H1 + l]) + __half2float(h1h[s3 * H1 + l]);
    }
    for (; j < e1; ++j) acc += __half2float(h1h[(int)eop[j] * H1 + l]);
    float di = dinv[node];
    float s  = acc + __half2float(h1h[node * H1 + l]);   // + self-loop
    float h  = fmaxf(fmaf(di, s, b1[l]), 0.f);
    float p0 = h * W2[2 * l], p1 = h * W2[2 * l + 1];
#pragma unroll
    for (int off = 1; off < 16; off <<= 1) {
        p0 += __shfl_xor(p0, off);
        p1 += __shfl_xor(p1, off);
    }
    if (l == 0) h2f[node] = make_float2(p0 * di, p1 * di);
}

// ---- layer-2 agg: 4 lanes/node + b2 + log_softmax ----
__global__ __launch_bounds__(256) void k_agg2(const unsigned int* __restrict__ eop,
                                              const int* __restrict__ nstart,
                                              const int* __restrict__ ndeg,
                                              const float2* __restrict__ h2f,
                                              const float* __restrict__ dinv,
                                              const float* __restrict__ b2,
                                              float* __restrict__ out) {
    int tg = blockIdx.x * 256 + threadIdx.x;
    int node = tg >> 2, l = tg & 3;
    if (node >= N_NODES) return;
    int e0 = nstart[node], e1 = e0 + ndeg[node];
    float ax = 0.f, ay = 0.f;
    for (int j = e0 + l; j < e1; j += 4) {
        float2 m = h2f[eop[j]];
        ax += m.x; ay += m.y;
    }
    ax += __shfl_xor(ax, 1); ay += __shfl_xor(ay, 1);
    ax += __shfl_xor(ax, 2); ay += __shfl_xor(ay, 2);
    if (l == 0) {
        float di = dinv[node];
        float2 self = h2f[node];
        float a0 = fmaf(di, ax + self.x, b2[0]);
        float a1 = fmaf(di, ay + self.y, b2[1]);
        float m  = fmaxf(a0, a1);
        float lg = logf(expf(a0 - m) + expf(a1 - m));
        out[2 * node]     = a0 - m - lg;
        out[2 * node + 1] = a1 - m - lg;
    }
}

extern "C" void kernel_launch(void* const* d_in, const int* in_sizes, int n_in,
                              void* d_out, int out_size, void* d_ws, size_t ws_size,
                              hipStream_t stream) {
    const float* x  = (const float*)d_in[0];
    const int*   ei = (const int*)d_in[1];
    const float* W1 = (const float*)d_in[2];
    const float* b1 = (const float*)d_in[3];
    const float* W2 = (const float*)d_in[4];
    const float* b2 = (const float*)d_in[5];
    float* out = (float*)d_out;

    // workspace carve (~25.6 MB); eop base offset 5220352 B = 64B-aligned
    int*          cursor = (int*)d_ws;                       // 512
    int*          nstart = cursor + 512;                     // N (pad 100352)
    int*          ndeg   = nstart + 100352;                  // N (pad 100352)
    float*        dinv   = (float*)(ndeg + 100352);          // N (pad 100352)
    __half*       h1h    = (__half*)(dinv + 100352);         // N*16 halves, 3.2 MB
    float2*       h2f    = (float2*)(h1h + (size_t)100352 * H1);  // N float2
    unsigned int* eop    = (unsigned int*)(h2f + 100352);    // NB*CAP = 20.4 MB

    k_zero     <<<1,    512, 0, stream>>>(cursor);
    k_partition<<<PBLK, 512, 0, stream>>>(ei, cursor, eop);
    k_build    <<<NB,   512, 0, stream>>>(cursor, eop, nstart, ndeg, dinv);
    k_mm1      <<<(N_NODES + MROWS - 1) / MROWS, 256, 0, stream>>>(x, W1, dinv, h1h);
    k_agg1     <<<N_NODES / 16, 256, 0, stream>>>(eop, nstart, ndeg, h1h, dinv, b1, W2, h2f);
    k_agg2     <<<(N_NODES * 4 + 255) / 256, 256, 0, stream>>>(eop, nstart, ndeg, h2f, dinv, b2, out);
}